// Round 13
// baseline (148.587 us; speedup 1.0000x reference)
//
#include <hip/hip_runtime.h>

// Problem constants (fixed by the reference's setup_inputs)
#define C_DIM 64
#define P_DIM 16
#define K_DIM 9
#define ZROW 10              // padded Zb row (ushorts) per (n,p): 20 B
#define ZNODE (P_DIM * ZROW) // 160 ushorts = 320 B per node
#define NT 9                 // n-tiles of 16 real output slots (144 total)
#define INV2S 0.35355339059327373f  // 1/(2*sqrt(2))

typedef __attribute__((ext_vector_type(8))) short short8v;  // 8 bf16 (4 VGPRs)
typedef __attribute__((ext_vector_type(4))) float f32x4;    // MFMA accumulator
typedef uint uint4a __attribute__((ext_vector_type(4), aligned(4)));

__device__ __forceinline__ ushort f2bf(float f) {
    uint u = __builtin_bit_cast(uint, f);
    return (ushort)((u + 0x7FFFu + ((u >> 16) & 1u)) >> 16);   // RNE
}
__device__ __forceinline__ float bf2f(ushort h) {
    return __builtin_bit_cast(float, ((uint)h) << 16);
}

// LDS row stride (in ushorts) for the W hi/lo tables: 72*2B = 144B rows,
// 16B aligned; ds_read_b128 lane bank stride 36%32=4 -> <=2-way (free).
#define WSTRIDE 72

// ---------------------------------------------------------------------------
// Kernel 1 (MFMA) — r2's measured-best 2-dispatch gemm (X=35.3us):
// (a) bias-init out, (b) pose -> packed-bf16 table (gated),
// (c) Zb[n][zi] = sum_c x[n,c]*W[p,k,c] via split-bf16 3-product MFMA,
// where zi = j + j/9 maps the j = p*9+k output slot into the PADDED
// 10-per-p layout (3 VALU ops per nt, outside the store loop). Pad slots
// are never written; the edge's window algebra never selects them.
// 64 rows/block, 4 waves; LINEAR W staging (no permute), NT=9.
// ---------------------------------------------------------------------------
__global__ __launch_bounds__(256) void z_gemm_kernel(const float* __restrict__ x,
                                                     const float* __restrict__ W,
                                                     const float* __restrict__ bias,
                                                     const float* __restrict__ pose,
                                                     float* __restrict__ out,
                                                     ushort* __restrict__ Zb,
                                                     uint* __restrict__ pose_bf,
                                                     int N) {
    __shared__ ushort w_hi[144 * WSTRIDE];   // 20736 B
    __shared__ ushort w_lo[144 * WSTRIDE];   // 20736 B

    const int tid = threadIdx.x;
    const int block_row = blockIdx.x * 64;

    // (a) bias-init this block's slice of out: 64 rows x 16 = 256 float4s
    {
        const float4 b4 = ((const float4*)bias)[tid & 3];
        const int o4 = block_row * 4 + tid;          // float4 index into out
        if (o4 < N * 4) ((float4*)out)[o4] = b4;
    }

    // (b) pose -> packed bf16 (measured -3us on edge_kernel, r4 vs r5)
    if (pose_bf != nullptr) {
        for (int i = tid; i < 64 * P_DIM; i += 256) {
            const int r = block_row + (i >> 4);
            if (r < N) {
                const float2 ab = ((const float2*)pose)[(size_t)r * P_DIM + (i & 15)];
                pose_bf[(size_t)r * P_DIM + (i & 15)] =
                    (uint)f2bf(ab.x) | ((uint)f2bf(ab.y) << 16);
            }
        }
    }

    // (c) stage W (144x64 f32 -> bf16 hi/lo), LINEAR: 4608 float2 loads
    for (int i = tid; i < 144 * (C_DIM / 2); i += 256) {
        const int n  = i >> 5;           // W row (0..143)
        const int k2 = i & 31;           // float2 index within row
        const float2 w2 = ((const float2*)W)[i];
        const int o = n * WSTRIDE + k2 * 2;
        const ushort h0 = f2bf(w2.x);
        const ushort h1 = f2bf(w2.y);
        w_hi[o]     = h0;
        w_hi[o + 1] = h1;
        w_lo[o]     = f2bf(w2.x - bf2f(h0));
        w_lo[o + 1] = f2bf(w2.y - bf2f(h1));
    }
    __syncthreads();

    const int lane = tid & 63;
    const int wv   = tid >> 6;    // wave -> m-subtile (16 rows)
    const int col  = lane & 15;   // A row within tile / B,C/D column
    const int kg   = lane >> 4;   // k-group 0..3

    // A operand: lane supplies x[arow][kg*8 + e (+32*chunk)], split hi/lo.
    const int arow = block_row + wv * 16 + col;
    const float* xr = x + (size_t)(arow < N ? arow : 0) * C_DIM;
    float4 x0 = ((const float4*)xr)[kg * 2];
    float4 x1 = ((const float4*)xr)[kg * 2 + 1];
    float4 x2 = ((const float4*)xr)[8 + kg * 2];
    float4 x3 = ((const float4*)xr)[8 + kg * 2 + 1];
    if (arow >= N) {
        x0 = x1 = x2 = x3 = make_float4(0.f, 0.f, 0.f, 0.f);
    }

    short8v a_hi0, a_lo0, a_hi1, a_lo1;
    {
        const float t0[8] = {x0.x, x0.y, x0.z, x0.w, x1.x, x1.y, x1.z, x1.w};
        const float t1[8] = {x2.x, x2.y, x2.z, x2.w, x3.x, x3.y, x3.z, x3.w};
        #pragma unroll
        for (int e = 0; e < 8; ++e) {
            const ushort h = f2bf(t0[e]);
            a_hi0[e] = (short)h;
            a_lo0[e] = (short)f2bf(t0[e] - bf2f(h));
            const ushort g = f2bf(t1[e]);
            a_hi1[e] = (short)g;
            a_lo1[e] = (short)f2bf(t1[e] - bf2f(g));
        }
    }

    // C/D layout (HW-verified): col = lane&15, row = kg*4 + reg
    const int orow0 = block_row + wv * 16 + kg * 4;

    #pragma unroll
    for (int nt = 0; nt < NT; ++nt) {
        const int j = nt * 16 + col;            // logical slot (0..143)
        const ushort* bhp = &w_hi[j * WSTRIDE + kg * 8];
        const ushort* blp = &w_lo[j * WSTRIDE + kg * 8];
        const short8v bh0 = *(const short8v*)bhp;          // c = kg*8+e
        const short8v bh1 = *(const short8v*)(bhp + 32);   // c = 32+kg*8+e
        const short8v bl0 = *(const short8v*)blp;
        const short8v bl1 = *(const short8v*)(blp + 32);

        f32x4 acc = {0.f, 0.f, 0.f, 0.f};
        // split-bf16 3-product: lo terms first, hi*hi last
        acc = __builtin_amdgcn_mfma_f32_16x16x32_bf16(a_lo0, bh0, acc, 0, 0, 0);
        acc = __builtin_amdgcn_mfma_f32_16x16x32_bf16(a_hi0, bl0, acc, 0, 0, 0);
        acc = __builtin_amdgcn_mfma_f32_16x16x32_bf16(a_lo1, bh1, acc, 0, 0, 0);
        acc = __builtin_amdgcn_mfma_f32_16x16x32_bf16(a_hi1, bl1, acc, 0, 0, 0);
        acc = __builtin_amdgcn_mfma_f32_16x16x32_bf16(a_hi0, bh0, acc, 0, 0, 0);
        acc = __builtin_amdgcn_mfma_f32_16x16x32_bf16(a_hi1, bh1, acc, 0, 0, 0);

        // padded slot: zi = j + j/9, with j/9 = (j*57)>>9 for j<144
        const int zi = j + ((j * 57) >> 9);
        #pragma unroll
        for (int r = 0; r < 4; ++r) {
            const int row = orow0 + r;
            if (row < N) Zb[(size_t)row * ZNODE + zi] = f2bf(acc[r]);
        }
    }
}

// ---------------------------------------------------------------------------
// Kernel 2: edge messages + scatter-add (unsorted) — r7/r10 measured-best
// structure (57.4us), EILP 8. Eager whole-row Zb loads (dwordx4 + dword)
// keep the gather chain at 2 serial miss levels; 4 spline taps selected
// in-register from the 6-halfword window at 3*b1. Pad halfword 9 of each
// row is garbage but provably never selected (b1=1 uses only halfword 8).
// ---------------------------------------------------------------------------
#define EILP 8
template <bool USEBF>
__global__ __launch_bounds__(256) void edge_kernel(const int* __restrict__ ei,
                                                   const float* __restrict__ pos,
                                                   const float* __restrict__ pose,
                                                   const uint* __restrict__ pose_bf,
                                                   const ushort* __restrict__ Zb,
                                                   float* __restrict__ out,
                                                   int E) {
    const int p  = threadIdx.x & 15;
    const int eg = threadIdx.x >> 4;
    const int e0 = blockIdx.x * (16 * EILP) + eg;

    int  r[EILP], c[EILP];
    bool valid[EILP];
    #pragma unroll
    for (int it = 0; it < EILP; ++it) {
        int e = e0 + it * 16;
        valid[it] = (e < E);
        int ec = valid[it] ? e : 0;
        r[it] = ei[ec];
        c[it] = ei[E + ec];
    }

    // --- eager independent gathers: pos, pose, and the full Zb row ---
    float d0[EILP], d1[EILP];
    #pragma unroll
    for (int it = 0; it < EILP; ++it) {
        const float2 pc = ((const float2*)pos)[c[it]];
        const float2 pr = ((const float2*)pos)[r[it]];
        d0[it] = (pc.x - pr.x) * INV2S;
        d1[it] = (pc.y - pr.y) * INV2S;
    }

    float a_[EILP], b_[EILP];
    #pragma unroll
    for (int it = 0; it < EILP; ++it) {
        if (USEBF) {
            const uint ab = pose_bf[(size_t)r[it] * P_DIM + p];
            a_[it] = bf2f((ushort)(ab & 0xffffu));
            b_[it] = bf2f((ushort)(ab >> 16));
        } else {
            const float2 ab = ((const float2*)pose)[(size_t)r[it] * P_DIM + p];
            a_[it] = ab.x;
            b_[it] = ab.y;
        }
    }

    uint4a qv[EILP];
    uint   q4[EILP];
    #pragma unroll
    for (int it = 0; it < EILP; ++it) {
        const uint* Zp = (const uint*)(Zb + (size_t)c[it] * ZNODE) + p * (ZROW / 2);
        qv[it] = *(const uint4a*)Zp;   // dwordx4 (4B-aligned ok on gfx9+)
        q4[it] = Zp[4];
    }

    #pragma unroll
    for (int it = 0; it < EILP; ++it) {
        const float p0 = fmaf(a_[it], d0[it], fmaf(-b_[it], d1[it], 0.5f));
        const float p1 = fmaf(b_[it], d0[it], fmaf( a_[it], d1[it], 0.5f));

        const float v0 = fminf(fmaxf(p0, 0.0f), 1.0f) * 2.0f;
        const float v1 = fminf(fmaxf(p1, 0.0f), 1.0f) * 2.0f;
        // window base: b0 = (v0>=1), b1 = (v1>=1); fracs relative to base.
        // (at v==2: base 1, frac 1 -> weight on column 2; matches the
        //  reference's clamped i00==i01==2 case exactly)
        const bool b0 = (v0 >= 1.0f);
        const bool b1 = (v1 >= 1.0f);
        const float f0 = v0 - (b0 ? 1.0f : 0.0f);
        const float f1 = v1 - (b1 ? 1.0f : 0.0f);

        // 6-element window w0..w5 = e(3*b1) .. e(3*b1+5) as 3 dwords
        const uint A0 = qv[it][0], A1 = qv[it][1], A2 = qv[it][2],
                   A3 = qv[it][3], A4 = q4[it];
        const uint W0 = b1 ? ((A1 >> 16) | (A2 << 16)) : A0;
        const uint W1 = b1 ? ((A2 >> 16) | (A3 << 16)) : A1;
        const uint W2 = b1 ? ((A3 >> 16) | (A4 << 16)) : A2;
        // taps: z00=w(b0), z10=w(b0+1), z01=w(b0+3), z11=w(b0+4)
        const uint s = b0 ? 16u : 0u;
        const float z00 = bf2f((ushort)(W0 >> s));
        const float z10 = bf2f((ushort)(b0 ? (W1 & 0xffffu) : (W0 >> 16)));
        const float z01 = bf2f((ushort)(b0 ? (W2 & 0xffffu) : (W1 >> 16)));
        const float z11 = bf2f((ushort)(W2 >> s));

        const float w00 = (1.0f - f0) * (1.0f - f1);
        const float w01 = (1.0f - f0) * f1;
        const float w10 = f0 * (1.0f - f1);
        const float w11 = f0 * f1;

        float m = w00 * z00;
        m = fmaf(w01, z01, m);
        m = fmaf(w10, z10, m);
        m = fmaf(w11, z11, m);

        if (valid[it]) atomicAdd(&out[(size_t)r[it] * P_DIM + p], m);
    }
}

// ---------------------------------------------------------------------------
extern "C" void kernel_launch(void* const* d_in, const int* in_sizes, int n_in,
                              void* d_out, int out_size, void* d_ws, size_t ws_size,
                              hipStream_t stream) {
    const float* x    = (const float*)d_in[0];
    const float* pos  = (const float*)d_in[1];
    const float* pose = (const float*)d_in[2];
    const float* W    = (const float*)d_in[3];
    const float* bias = (const float*)d_in[4];
    const int*   ei   = (const int*)d_in[5];

    const int N = in_sizes[0] / C_DIM;   // 50000
    const int E = in_sizes[5] / 2;       // 800000

    float* out = (float*)d_out;
    ushort* Zb = (ushort*)d_ws;          // N*160 bf16 = 16.0 MB (padded rows)

    // pose-bf16 table only if the workspace actually has room for it
    const size_t zb_bytes   = (size_t)N * ZNODE * sizeof(ushort);
    const size_t pose_bytes = (size_t)N * P_DIM * sizeof(uint);
    uint* pose_bf = (ws_size >= zb_bytes + pose_bytes)
                        ? (uint*)((char*)d_ws + zb_bytes) : nullptr;

    z_gemm_kernel<<<(N + 63) / 64, 256, 0, stream>>>(x, W, bias, pose, out, Zb, pose_bf, N);

    const int eblocks = (E + 16 * EILP - 1) / (16 * EILP);
    if (pose_bf != nullptr)
        edge_kernel<true><<<eblocks, 256, 0, stream>>>(ei, pos, pose, pose_bf, Zb, out, E);
    else
        edge_kernel<false><<<eblocks, 256, 0, stream>>>(ei, pos, pose, pose_bf, Zb, out, E);
}

// Round 14
// 145.919 us; speedup vs baseline: 1.0183x; 1.0183x over previous
//
#include <hip/hip_runtime.h>

// Problem constants (fixed by the reference's setup_inputs)
#define C_DIM 64
#define P_DIM 16
#define K_DIM 9
#define ZROW 10              // padded Zb row (ushorts) per (n,p): 20 B
#define ZNODE (P_DIM * ZROW) // 160 ushorts = 320 B per node
#define NT 10                // j-tiles (permuted 160-slot padded layout)
#define WELEM (160 * C_DIM)  // ushorts per W' table (10240)
#define INV2S 0.35355339059327373f  // 1/(2*sqrt(2))

typedef __attribute__((ext_vector_type(8))) short short8v;  // 8 bf16 (4 VGPRs)
typedef __attribute__((ext_vector_type(4))) float f32x4;    // MFMA accumulator
typedef uint uint4a __attribute__((ext_vector_type(4), aligned(4)));

__device__ __forceinline__ ushort f2bf(float f) {
    uint u = __builtin_bit_cast(uint, f);
    return (ushort)((u + 0x7FFFu + ((u >> 16) & 1u)) >> 16);   // RNE
}
__device__ __forceinline__ float bf2f(ushort h) {
    return __builtin_bit_cast(float, ((uint)h) << 16);
}

// ---------------------------------------------------------------------------
// Kernel 0 (prep, one-shot): (a) permuted W' -> global bf16 hi/lo tables
// (row j holds W[(j/10)*9 + j%10], zeros at j%10==9), (b) pose -> packed
// bf16 table, (c) bias-init of out.
// ---------------------------------------------------------------------------
__global__ __launch_bounds__(256) void prep_kernel(const float* __restrict__ W,
                                                   const float* __restrict__ pose,
                                                   const float* __restrict__ bias,
                                                   float* __restrict__ out,
                                                   ushort* __restrict__ Whi,
                                                   ushort* __restrict__ Wlo,
                                                   uint* __restrict__ pose_bf,
                                                   int N) {
    const int g = blockIdx.x * 256 + threadIdx.x;
    const int gsz = gridDim.x * 256;

    // (a) W' tables: 5120 dwords per table
    if (g < WELEM / 2) {
        const int j  = g >> 5;           // W' row (0..159)
        const int k2 = g & 31;           // float2 index within row
        const int p  = j / 10;
        const int k  = j - p * 10;
        float2 w2 = make_float2(0.0f, 0.0f);
        if (k < 9) w2 = ((const float2*)W)[(p * 9 + k) * (C_DIM / 2) + k2];
        const ushort h0 = f2bf(w2.x);
        const ushort h1 = f2bf(w2.y);
        ((uint*)Whi)[g] = (uint)h0 | ((uint)h1 << 16);
        ((uint*)Wlo)[g] = (uint)f2bf(w2.x - bf2f(h0)) |
                          ((uint)f2bf(w2.y - bf2f(h1)) << 16);
    }

    // (b) pose -> packed bf16 (measured -3us on edge, r4 vs r5)
    if (pose_bf != nullptr) {
        for (int i = g; i < N * P_DIM; i += gsz) {
            const float2 ab = ((const float2*)pose)[i];
            pose_bf[i] = (uint)f2bf(ab.x) | ((uint)f2bf(ab.y) << 16);
        }
    }

    // (c) bias-init out: N*4 float4s
    {
        const float4 b4 = ((const float4*)bias)[g & 3];
        for (int i = g; i < N * 4; i += gsz) ((float4*)out)[i] = b4;
    }
}

// ---------------------------------------------------------------------------
// Kernel 1 (MFMA): Zb[n][j] (j = padded slot) = sum_c x[n,c]*W'[j,c] via
// split-bf16 3-product MFMA with SWAPPED operands: A = W' fragment,
// B = x fragment (both fetch paths identical to before — A/B layouts are
// mutual transposes). C/D map (col=lane&15, row=kg*4+reg) then gives each
// lane Z[n=col][kg*4 .. kg*4+3]: 4 consecutive padded slots -> ONE aligned
// 8B store. Stores/wave: 40 -> 10. Pad slots get exact 0.0 (zero W' rows).
// Staging = pure vector copy of prepped tables, XOR-swizzled LDS
// (half ^= (row&7)<<3) applied identically on write and read.
// ---------------------------------------------------------------------------
__global__ __launch_bounds__(256) void z_gemm_kernel(const float* __restrict__ x,
                                                     const ushort* __restrict__ Whi,
                                                     const ushort* __restrict__ Wlo,
                                                     ushort* __restrict__ Zb,
                                                     int N) {
    __shared__ ushort w_hi[WELEM];   // 20480 B
    __shared__ ushort w_lo[WELEM];   // 20480 B

    const int tid = threadIdx.x;
    const int block_row = blockIdx.x * 64;

    // stage both tables: 160*16 uint4s each, swizzled LDS dest
    for (int i = tid; i < 160 * 16; i += 256) {
        const uint4 vh = ((const uint4*)Whi)[i];
        const uint4 vl = ((const uint4*)Wlo)[i];
        const int lin = i * 8;                    // half-offset (mult of 8)
        const int j   = lin >> 6;                 // row
        const int w   = lin & 63;
        const int swz = j * 64 + (w ^ ((j & 7) << 3));
        *(uint4*)&w_hi[swz] = vh;
        *(uint4*)&w_lo[swz] = vl;
    }
    __syncthreads();

    const int lane = tid & 63;
    const int wv   = tid >> 6;    // wave -> 16-row n-subtile
    const int col  = lane & 15;   // x row within subtile / W' row in j-tile
    const int kg   = lane >> 4;   // k-group 0..3

    // x operand (B): lane supplies x[arow][kg*8 + e (+32*chunk)], split hi/lo.
    const int arow = block_row + wv * 16 + col;
    const float* xr = x + (size_t)(arow < N ? arow : 0) * C_DIM;
    float4 x0 = ((const float4*)xr)[kg * 2];
    float4 x1 = ((const float4*)xr)[kg * 2 + 1];
    float4 x2 = ((const float4*)xr)[8 + kg * 2];
    float4 x3 = ((const float4*)xr)[8 + kg * 2 + 1];
    if (arow >= N) {
        x0 = x1 = x2 = x3 = make_float4(0.f, 0.f, 0.f, 0.f);
    }

    short8v a_hi0, a_lo0, a_hi1, a_lo1;
    {
        const float t0[8] = {x0.x, x0.y, x0.z, x0.w, x1.x, x1.y, x1.z, x1.w};
        const float t1[8] = {x2.x, x2.y, x2.z, x2.w, x3.x, x3.y, x3.z, x3.w};
        #pragma unroll
        for (int e = 0; e < 8; ++e) {
            const ushort h = f2bf(t0[e]);
            a_hi0[e] = (short)h;
            a_lo0[e] = (short)f2bf(t0[e] - bf2f(h));
            const ushort g = f2bf(t1[e]);
            a_hi1[e] = (short)g;
            a_lo1[e] = (short)f2bf(t1[e] - bf2f(g));
        }
    }

    ushort* zrow = Zb + (size_t)arow * ZNODE;   // this lane's output row

    #pragma unroll
    for (int jt = 0; jt < NT; ++jt) {
        const int j  = jt * 16 + col;             // W' row (A-row) for LDS read
        const int sx = (j & 7) << 3;              // row swizzle
        const int b0off = j * 64 + ((kg * 8) ^ sx);
        const int b1off = j * 64 + ((32 + kg * 8) ^ sx);
        const short8v bh0 = *(const short8v*)&w_hi[b0off];
        const short8v bh1 = *(const short8v*)&w_hi[b1off];
        const short8v bl0 = *(const short8v*)&w_lo[b0off];
        const short8v bl1 = *(const short8v*)&w_lo[b1off];

        f32x4 acc = {0.f, 0.f, 0.f, 0.f};
        // split-bf16 3-product, operands SWAPPED (A=W', B=x): same product
        // set & k-pairing as before -> bitwise-identical sums. lo first.
        acc = __builtin_amdgcn_mfma_f32_16x16x32_bf16(bh0, a_lo0, acc, 0, 0, 0);
        acc = __builtin_amdgcn_mfma_f32_16x16x32_bf16(bl0, a_hi0, acc, 0, 0, 0);
        acc = __builtin_amdgcn_mfma_f32_16x16x32_bf16(bh1, a_lo1, acc, 0, 0, 0);
        acc = __builtin_amdgcn_mfma_f32_16x16x32_bf16(bl1, a_hi1, acc, 0, 0, 0);
        acc = __builtin_amdgcn_mfma_f32_16x16x32_bf16(bh0, a_hi0, acc, 0, 0, 0);
        acc = __builtin_amdgcn_mfma_f32_16x16x32_bf16(bh1, a_hi1, acc, 0, 0, 0);

        // lane holds Z[arow][jt*16 + kg*4 + (0..3)] -> one aligned 8B store
        if (arow < N) {
            uint2 v;
            v.x = (uint)f2bf(acc[0]) | ((uint)f2bf(acc[1]) << 16);
            v.y = (uint)f2bf(acc[2]) | ((uint)f2bf(acc[3]) << 16);
            *(uint2*)(zrow + jt * 16 + kg * 4) = v;
        }
    }
}

// ---------------------------------------------------------------------------
// Kernel 2: edge messages + scatter-add (unsorted) — r7/r10 measured-best
// structure (57.4us), EILP 8. Eager whole-row Zb loads (dwordx4 + dword)
// keep the gather chain at 2 serial miss levels; 4 spline taps selected
// in-register from the 6-halfword window at 3*b1.
// ---------------------------------------------------------------------------
#define EILP 8
template <bool USEBF>
__global__ __launch_bounds__(256) void edge_kernel(const int* __restrict__ ei,
                                                   const float* __restrict__ pos,
                                                   const float* __restrict__ pose,
                                                   const uint* __restrict__ pose_bf,
                                                   const ushort* __restrict__ Zb,
                                                   float* __restrict__ out,
                                                   int E) {
    const int p  = threadIdx.x & 15;
    const int eg = threadIdx.x >> 4;
    const int e0 = blockIdx.x * (16 * EILP) + eg;

    int  r[EILP], c[EILP];
    bool valid[EILP];
    #pragma unroll
    for (int it = 0; it < EILP; ++it) {
        int e = e0 + it * 16;
        valid[it] = (e < E);
        int ec = valid[it] ? e : 0;
        r[it] = ei[ec];
        c[it] = ei[E + ec];
    }

    // --- eager independent gathers: pos, pose, and the full Zb row ---
    float d0[EILP], d1[EILP];
    #pragma unroll
    for (int it = 0; it < EILP; ++it) {
        const float2 pc = ((const float2*)pos)[c[it]];
        const float2 pr = ((const float2*)pos)[r[it]];
        d0[it] = (pc.x - pr.x) * INV2S;
        d1[it] = (pc.y - pr.y) * INV2S;
    }

    float a_[EILP], b_[EILP];
    #pragma unroll
    for (int it = 0; it < EILP; ++it) {
        if (USEBF) {
            const uint ab = pose_bf[(size_t)r[it] * P_DIM + p];
            a_[it] = bf2f((ushort)(ab & 0xffffu));
            b_[it] = bf2f((ushort)(ab >> 16));
        } else {
            const float2 ab = ((const float2*)pose)[(size_t)r[it] * P_DIM + p];
            a_[it] = ab.x;
            b_[it] = ab.y;
        }
    }

    uint4a qv[EILP];
    uint   q4[EILP];
    #pragma unroll
    for (int it = 0; it < EILP; ++it) {
        const uint* Zp = (const uint*)(Zb + (size_t)c[it] * ZNODE) + p * (ZROW / 2);
        qv[it] = *(const uint4a*)Zp;   // dwordx4 (4B-aligned ok on gfx9+)
        q4[it] = Zp[4];
    }

    #pragma unroll
    for (int it = 0; it < EILP; ++it) {
        const float p0 = fmaf(a_[it], d0[it], fmaf(-b_[it], d1[it], 0.5f));
        const float p1 = fmaf(b_[it], d0[it], fmaf( a_[it], d1[it], 0.5f));

        const float v0 = fminf(fmaxf(p0, 0.0f), 1.0f) * 2.0f;
        const float v1 = fminf(fmaxf(p1, 0.0f), 1.0f) * 2.0f;
        // window base: b0 = (v0>=1), b1 = (v1>=1); fracs relative to base.
        // (at v==2: base 1, frac 1 -> weight on column 2; matches the
        //  reference's clamped i00==i01==2 case exactly)
        const bool b0 = (v0 >= 1.0f);
        const bool b1 = (v1 >= 1.0f);
        const float f0 = v0 - (b0 ? 1.0f : 0.0f);
        const float f1 = v1 - (b1 ? 1.0f : 0.0f);

        // 6-element window w0..w5 = e(3*b1) .. e(3*b1+5) as 3 dwords
        const uint A0 = qv[it][0], A1 = qv[it][1], A2 = qv[it][2],
                   A3 = qv[it][3], A4 = q4[it];
        const uint W0 = b1 ? ((A1 >> 16) | (A2 << 16)) : A0;
        const uint W1 = b1 ? ((A2 >> 16) | (A3 << 16)) : A1;
        const uint W2 = b1 ? ((A3 >> 16) | (A4 << 16)) : A2;
        // taps: z00=w(b0), z10=w(b0+1), z01=w(b0+3), z11=w(b0+4)
        const uint s = b0 ? 16u : 0u;
        const float z00 = bf2f((ushort)(W0 >> s));
        const float z10 = bf2f((ushort)(b0 ? (W1 & 0xffffu) : (W0 >> 16)));
        const float z01 = bf2f((ushort)(b0 ? (W2 & 0xffffu) : (W1 >> 16)));
        const float z11 = bf2f((ushort)(W2 >> s));

        const float w00 = (1.0f - f0) * (1.0f - f1);
        const float w01 = (1.0f - f0) * f1;
        const float w10 = f0 * (1.0f - f1);
        const float w11 = f0 * f1;

        float m = w00 * z00;
        m = fmaf(w01, z01, m);
        m = fmaf(w10, z10, m);
        m = fmaf(w11, z11, m);

        if (valid[it]) atomicAdd(&out[(size_t)r[it] * P_DIM + p], m);
    }
}

// ---------------------------------------------------------------------------
extern "C" void kernel_launch(void* const* d_in, const int* in_sizes, int n_in,
                              void* d_out, int out_size, void* d_ws, size_t ws_size,
                              hipStream_t stream) {
    const float* x    = (const float*)d_in[0];
    const float* pos  = (const float*)d_in[1];
    const float* pose = (const float*)d_in[2];
    const float* W    = (const float*)d_in[3];
    const float* bias = (const float*)d_in[4];
    const int*   ei   = (const int*)d_in[5];

    const int N = in_sizes[0] / C_DIM;   // 50000
    const int E = in_sizes[5] / 2;       // 800000

    float* out = (float*)d_out;

    // workspace layout: [Whi 20KB][Wlo 20KB][Zb 16MB][pose_bf 3.2MB gated]
    ushort* Whi = (ushort*)d_ws;
    ushort* Wlo = Whi + WELEM;
    ushort* Zb  = Wlo + WELEM;

    const size_t w_bytes    = (size_t)2 * WELEM * sizeof(ushort);
    const size_t zb_bytes   = (size_t)N * ZNODE * sizeof(ushort);
    const size_t pose_bytes = (size_t)N * P_DIM * sizeof(uint);
    uint* pose_bf = (ws_size >= w_bytes + zb_bytes + pose_bytes)
                        ? (uint*)((char*)Zb + zb_bytes) : nullptr;

    prep_kernel<<<3200, 256, 0, stream>>>(W, pose, bias, out, Whi, Wlo, pose_bf, N);
    z_gemm_kernel<<<(N + 63) / 64, 256, 0, stream>>>(x, Whi, Wlo, Zb, N);

    const int eblocks = (E + 16 * EILP - 1) / (16 * EILP);
    if (pose_bf != nullptr)
        edge_kernel<true><<<eblocks, 256, 0, stream>>>(ei, pos, pose, pose_bf, Zb, out, E);
    else
        edge_kernel<false><<<eblocks, 256, 0, stream>>>(ei, pos, pose, pose_bf, Zb, out, E);
}

// Round 15
// 145.364 us; speedup vs baseline: 1.0222x; 1.0038x over previous
//
#include <hip/hip_runtime.h>

// Problem constants (fixed by the reference's setup_inputs)
#define C_DIM 64
#define P_DIM 16
#define K_DIM 9
#define ZROW 10              // padded Zb row (ushorts) per (n,p): 20 B
#define ZNODE (P_DIM * ZROW) // 160 ushorts = 320 B per node
#define NT 10                // n-tiles (permuted 160-slot output layout)
#define WELEM (160 * C_DIM)  // ushorts per W' table (10240)
#define INV2S 0.35355339059327373f  // 1/(2*sqrt(2))

typedef __attribute__((ext_vector_type(8))) short short8v;  // 8 bf16 (4 VGPRs)
typedef __attribute__((ext_vector_type(4))) float f32x4;    // MFMA accumulator
typedef uint uint4a __attribute__((ext_vector_type(4), aligned(4)));

__device__ __forceinline__ ushort f2bf(float f) {
    uint u = __builtin_bit_cast(uint, f);
    return (ushort)((u + 0x7FFFu + ((u >> 16) & 1u)) >> 16);   // RNE
}
__device__ __forceinline__ float bf2f(ushort h) {
    return __builtin_bit_cast(float, ((uint)h) << 16);
}

// ---------------------------------------------------------------------------
// Kernel 0 (prep, one-shot): (a) permuted W' -> global bf16 hi/lo tables
// (row j holds W[(j/10)*9 + j%10], zeros at j%10==9), (b) pose -> packed
// bf16 table, (c) bias-init of out.
// ---------------------------------------------------------------------------
__global__ __launch_bounds__(256) void prep_kernel(const float* __restrict__ W,
                                                   const float* __restrict__ pose,
                                                   const float* __restrict__ bias,
                                                   float* __restrict__ out,
                                                   ushort* __restrict__ Whi,
                                                   ushort* __restrict__ Wlo,
                                                   uint* __restrict__ pose_bf,
                                                   int N) {
    const int g = blockIdx.x * 256 + threadIdx.x;
    const int gsz = gridDim.x * 256;

    // (a) W' tables: 5120 dwords per table
    if (g < WELEM / 2) {
        const int j  = g >> 5;           // W' row (0..159)
        const int k2 = g & 31;           // float2 index within row
        const int p  = j / 10;
        const int k  = j - p * 10;
        float2 w2 = make_float2(0.0f, 0.0f);
        if (k < 9) w2 = ((const float2*)W)[(p * 9 + k) * (C_DIM / 2) + k2];
        const ushort h0 = f2bf(w2.x);
        const ushort h1 = f2bf(w2.y);
        ((uint*)Whi)[g] = (uint)h0 | ((uint)h1 << 16);
        ((uint*)Wlo)[g] = (uint)f2bf(w2.x - bf2f(h0)) |
                          ((uint)f2bf(w2.y - bf2f(h1)) << 16);
    }

    // (b) pose -> packed bf16 (measured -3us on edge, r4 vs r5)
    if (pose_bf != nullptr) {
        for (int i = g; i < N * P_DIM; i += gsz) {
            const float2 ab = ((const float2*)pose)[i];
            pose_bf[i] = (uint)f2bf(ab.x) | ((uint)f2bf(ab.y) << 16);
        }
    }

    // (c) bias-init out: N*4 float4s
    {
        const float4 b4 = ((const float4*)bias)[g & 3];
        for (int i = g; i < N * 4; i += gsz) ((float4*)out)[i] = b4;
    }
}

// ---------------------------------------------------------------------------
// Kernel 1 (MFMA): Zb[n][s] (s = p*10+k, padded) = sum_c x[n,c]*W[p,k,c]
// via split-bf16 3-product MFMA. 64 rows/block, 4 waves.
// Staging = pure vector copy of the prepped tables, XOR-swizzled LDS
// (half ^= (row&7)<<3) applied identically on write and read.
// ---------------------------------------------------------------------------
__global__ __launch_bounds__(256) void z_gemm_kernel(const float* __restrict__ x,
                                                     const ushort* __restrict__ Whi,
                                                     const ushort* __restrict__ Wlo,
                                                     ushort* __restrict__ Zb,
                                                     int N) {
    __shared__ ushort w_hi[WELEM];   // 20480 B
    __shared__ ushort w_lo[WELEM];   // 20480 B

    const int tid = threadIdx.x;
    const int block_row = blockIdx.x * 64;

    // stage both tables: 160*16 uint4s each, swizzled LDS dest
    for (int i = tid; i < 160 * 16; i += 256) {
        const uint4 vh = ((const uint4*)Whi)[i];
        const uint4 vl = ((const uint4*)Wlo)[i];
        const int lin = i * 8;                    // half-offset (mult of 8)
        const int j   = lin >> 6;                 // row
        const int w   = lin & 63;
        const int swz = j * 64 + (w ^ ((j & 7) << 3));
        *(uint4*)&w_hi[swz] = vh;
        *(uint4*)&w_lo[swz] = vl;
    }
    __syncthreads();

    const int lane = tid & 63;
    const int wv   = tid >> 6;    // wave -> m-subtile (16 rows)
    const int col  = lane & 15;   // A row within tile / B,C/D column
    const int kg   = lane >> 4;   // k-group 0..3

    // A operand: lane supplies x[arow][kg*8 + e (+32*chunk)], split hi/lo.
    const int arow = block_row + wv * 16 + col;
    const float* xr = x + (size_t)(arow < N ? arow : 0) * C_DIM;
    float4 x0 = ((const float4*)xr)[kg * 2];
    float4 x1 = ((const float4*)xr)[kg * 2 + 1];
    float4 x2 = ((const float4*)xr)[8 + kg * 2];
    float4 x3 = ((const float4*)xr)[8 + kg * 2 + 1];
    if (arow >= N) {
        x0 = x1 = x2 = x3 = make_float4(0.f, 0.f, 0.f, 0.f);
    }

    short8v a_hi0, a_lo0, a_hi1, a_lo1;
    {
        const float t0[8] = {x0.x, x0.y, x0.z, x0.w, x1.x, x1.y, x1.z, x1.w};
        const float t1[8] = {x2.x, x2.y, x2.z, x2.w, x3.x, x3.y, x3.z, x3.w};
        #pragma unroll
        for (int e = 0; e < 8; ++e) {
            const ushort h = f2bf(t0[e]);
            a_hi0[e] = (short)h;
            a_lo0[e] = (short)f2bf(t0[e] - bf2f(h));
            const ushort g = f2bf(t1[e]);
            a_hi1[e] = (short)g;
            a_lo1[e] = (short)f2bf(t1[e] - bf2f(g));
        }
    }

    // C/D layout (HW-verified): col = lane&15, row = kg*4 + reg
    const int orow0 = block_row + wv * 16 + kg * 4;

    #pragma unroll
    for (int nt = 0; nt < NT; ++nt) {
        const int j  = nt * 16 + col;             // padded slot (0..159)
        const int sx = (j & 7) << 3;              // row swizzle
        const int b0off = j * 64 + ((kg * 8) ^ sx);
        const int b1off = j * 64 + ((32 + kg * 8) ^ sx);
        const short8v bh0 = *(const short8v*)&w_hi[b0off];
        const short8v bh1 = *(const short8v*)&w_hi[b1off];
        const short8v bl0 = *(const short8v*)&w_lo[b0off];
        const short8v bl1 = *(const short8v*)&w_lo[b1off];

        f32x4 acc = {0.f, 0.f, 0.f, 0.f};
        // split-bf16 3-product: lo terms first, hi*hi last
        acc = __builtin_amdgcn_mfma_f32_16x16x32_bf16(a_lo0, bh0, acc, 0, 0, 0);
        acc = __builtin_amdgcn_mfma_f32_16x16x32_bf16(a_hi0, bl0, acc, 0, 0, 0);
        acc = __builtin_amdgcn_mfma_f32_16x16x32_bf16(a_lo1, bh1, acc, 0, 0, 0);
        acc = __builtin_amdgcn_mfma_f32_16x16x32_bf16(a_hi1, bl1, acc, 0, 0, 0);
        acc = __builtin_amdgcn_mfma_f32_16x16x32_bf16(a_hi0, bh0, acc, 0, 0, 0);
        acc = __builtin_amdgcn_mfma_f32_16x16x32_bf16(a_hi1, bh1, acc, 0, 0, 0);

        // direct store: slot == j; 16 col-lanes -> 32B contiguous chunks
        #pragma unroll
        for (int r = 0; r < 4; ++r) {
            const int row = orow0 + r;
            if (row < N) Zb[(size_t)row * ZNODE + j] = f2bf(acc[r]);
        }
    }
}

// ---------------------------------------------------------------------------
// Kernel 2: edge messages + scatter-add (unsorted), r7/r10 structure,
// EILP 8 (measured best: 57.4us). Eager whole-row Zb loads (dwordx4 +
// dword) keep the gather chain at 2 serial miss levels; 4 spline taps
// selected in-register from the 6-halfword window at 3*b1.
// ---------------------------------------------------------------------------
#define EILP 8
template <bool USEBF>
__global__ __launch_bounds__(256) void edge_kernel(const int* __restrict__ ei,
                                                   const float* __restrict__ pos,
                                                   const float* __restrict__ pose,
                                                   const uint* __restrict__ pose_bf,
                                                   const ushort* __restrict__ Zb,
                                                   float* __restrict__ out,
                                                   int E) {
    const int p  = threadIdx.x & 15;
    const int eg = threadIdx.x >> 4;
    const int e0 = blockIdx.x * (16 * EILP) + eg;

    int  r[EILP], c[EILP];
    bool valid[EILP];
    #pragma unroll
    for (int it = 0; it < EILP; ++it) {
        int e = e0 + it * 16;
        valid[it] = (e < E);
        int ec = valid[it] ? e : 0;
        r[it] = ei[ec];
        c[it] = ei[E + ec];
    }

    // --- eager independent gathers: pos, pose, and the full Zb row ---
    float d0[EILP], d1[EILP];
    #pragma unroll
    for (int it = 0; it < EILP; ++it) {
        const float2 pc = ((const float2*)pos)[c[it]];
        const float2 pr = ((const float2*)pos)[r[it]];
        d0[it] = (pc.x - pr.x) * INV2S;
        d1[it] = (pc.y - pr.y) * INV2S;
    }

    float a_[EILP], b_[EILP];
    #pragma unroll
    for (int it = 0; it < EILP; ++it) {
        if (USEBF) {
            const uint ab = pose_bf[(size_t)r[it] * P_DIM + p];
            a_[it] = bf2f((ushort)(ab & 0xffffu));
            b_[it] = bf2f((ushort)(ab >> 16));
        } else {
            const float2 ab = ((const float2*)pose)[(size_t)r[it] * P_DIM + p];
            a_[it] = ab.x;
            b_[it] = ab.y;
        }
    }

    uint4a qv[EILP];
    uint   q4[EILP];
    #pragma unroll
    for (int it = 0; it < EILP; ++it) {
        const uint* Zp = (const uint*)(Zb + (size_t)c[it] * ZNODE) + p * (ZROW / 2);
        qv[it] = *(const uint4a*)Zp;   // dwordx4 (4B-aligned ok on gfx9+)
        q4[it] = Zp[4];
    }

    #pragma unroll
    for (int it = 0; it < EILP; ++it) {
        const float p0 = fmaf(a_[it], d0[it], fmaf(-b_[it], d1[it], 0.5f));
        const float p1 = fmaf(b_[it], d0[it], fmaf( a_[it], d1[it], 0.5f));

        const float v0 = fminf(fmaxf(p0, 0.0f), 1.0f) * 2.0f;
        const float v1 = fminf(fmaxf(p1, 0.0f), 1.0f) * 2.0f;
        // window base: b0 = (v0>=1), b1 = (v1>=1); fracs relative to base.
        // (at v==2: base 1, frac 1 -> weight on column 2; matches the
        //  reference's clamped i00==i01==2 case exactly)
        const bool b0 = (v0 >= 1.0f);
        const bool b1 = (v1 >= 1.0f);
        const float f0 = v0 - (b0 ? 1.0f : 0.0f);
        const float f1 = v1 - (b1 ? 1.0f : 0.0f);

        // 6-element window w0..w5 = e(3*b1) .. e(3*b1+5) as 3 dwords
        const uint A0 = qv[it][0], A1 = qv[it][1], A2 = qv[it][2],
                   A3 = qv[it][3], A4 = q4[it];
        const uint W0 = b1 ? ((A1 >> 16) | (A2 << 16)) : A0;
        const uint W1 = b1 ? ((A2 >> 16) | (A3 << 16)) : A1;
        const uint W2 = b1 ? ((A3 >> 16) | (A4 << 16)) : A2;
        // taps: z00=w(b0), z10=w(b0+1), z01=w(b0+3), z11=w(b0+4)
        const uint s = b0 ? 16u : 0u;
        const float z00 = bf2f((ushort)(W0 >> s));
        const float z10 = bf2f((ushort)(b0 ? (W1 & 0xffffu) : (W0 >> 16)));
        const float z01 = bf2f((ushort)(b0 ? (W2 & 0xffffu) : (W1 >> 16)));
        const float z11 = bf2f((ushort)(W2 >> s));

        const float w00 = (1.0f - f0) * (1.0f - f1);
        const float w01 = (1.0f - f0) * f1;
        const float w10 = f0 * (1.0f - f1);
        const float w11 = f0 * f1;

        float m = w00 * z00;
        m = fmaf(w01, z01, m);
        m = fmaf(w10, z10, m);
        m = fmaf(w11, z11, m);

        if (valid[it]) atomicAdd(&out[(size_t)r[it] * P_DIM + p], m);
    }
}

// ---------------------------------------------------------------------------
extern "C" void kernel_launch(void* const* d_in, const int* in_sizes, int n_in,
                              void* d_out, int out_size, void* d_ws, size_t ws_size,
                              hipStream_t stream) {
    const float* x    = (const float*)d_in[0];
    const float* pos  = (const float*)d_in[1];
    const float* pose = (const float*)d_in[2];
    const float* W    = (const float*)d_in[3];
    const float* bias = (const float*)d_in[4];
    const int*   ei   = (const int*)d_in[5];

    const int N = in_sizes[0] / C_DIM;   // 50000
    const int E = in_sizes[5] / 2;       // 800000

    float* out = (float*)d_out;

    // workspace layout: [Whi 20KB][Wlo 20KB][Zb 16MB][pose_bf 3.2MB gated]
    ushort* Whi = (ushort*)d_ws;
    ushort* Wlo = Whi + WELEM;
    ushort* Zb  = Wlo + WELEM;

    const size_t w_bytes    = (size_t)2 * WELEM * sizeof(ushort);
    const size_t zb_bytes   = (size_t)N * ZNODE * sizeof(ushort);
    const size_t pose_bytes = (size_t)N * P_DIM * sizeof(uint);
    uint* pose_bf = (ws_size >= w_bytes + zb_bytes + pose_bytes)
                        ? (uint*)((char*)Zb + zb_bytes) : nullptr;

    prep_kernel<<<3200, 256, 0, stream>>>(W, pose, bias, out, Whi, Wlo, pose_bf, N);
    z_gemm_kernel<<<(N + 63) / 64, 256, 0, stream>>>(x, Whi, Wlo, Zb, N);

    const int eblocks = (E + 16 * EILP - 1) / (16 * EILP);
    if (pose_bf != nullptr)
        edge_kernel<true><<<eblocks, 256, 0, stream>>>(ei, pos, pose, pose_bf, Zb, out, E);
    else
        edge_kernel<false><<<eblocks, 256, 0, stream>>>(ei, pos, pose, pose_bf, Zb, out, E);
}